// Round 2
// baseline (487.089 us; speedup 1.0000x reference)
//
#include <hip/hip_runtime.h>

// PointPillarsScatter on MI355X.
// out[((b*C+c)*H+h)*W+w] = feat[owner(b, h*W+w), c], 0 where no owner.
// owner = argmax_p over pillars landing on the slot (last-wins overwrite
// semantics of sequential indexed assignment / jnp .at[].set()).

#define B_  8
#define C_  64
#define H_  496
#define W_  432
#define HW_ (H_ * W_)          // 214272 (divisible by 4)

// ---- pass 1: owner map = -1 --------------------------------------------
__global__ void pps_init_owner(int* __restrict__ owner, int n4) {
    int t = blockIdx.x * blockDim.x + threadIdx.x;
    if (t < n4) {
        ((int4*)owner)[t] = make_int4(-1, -1, -1, -1);
    }
}

// ---- pass 2: last-wins slot ownership via atomicMax --------------------
__global__ void pps_scatter_owner(const int* __restrict__ coords,
                                  int* __restrict__ owner, int P) {
    int p = blockIdx.x * blockDim.x + threadIdx.x;
    if (p >= P) return;
    int4 c = ((const int4*)coords)[p];       // (b, x, y, z)
    int idx = c.y * W_ + c.z;
    idx = min(max(idx, 0), HW_ - 1);         // clip, as in reference
    atomicMax(&owner[c.x * HW_ + idx], p);   // device-scope by default
}

// ---- pass 3: channel-loop gather, fuses zero-fill ----------------------
// One thread = 4 consecutive spatial positions x all 64 channels.
// Owner map read once; each pillar row read by exactly one thread.
__global__ __launch_bounds__(256) void pps_gather(
        const float* __restrict__ feat,      // [P, 64]
        const int*   __restrict__ owner,     // [B*HW]
        float*       __restrict__ out,       // [B, C, H, W]
        int nquads) {                        // B*HW/4
    int t = blockIdx.x * blockDim.x + threadIdx.x;
    if (t >= nquads) return;
    unsigned pos    = (unsigned)t * 4u;      // b*HW + within, %4 == 0
    unsigned b      = pos / HW_;             // magic-mul
    unsigned within = pos - b * HW_;

    int4 o = *(const int4*)&owner[pos];      // aligned: pos % 4 == 0
    const float* f0 = feat + (unsigned)(o.x < 0 ? 0 : o.x) * 64u;
    const float* f1 = feat + (unsigned)(o.y < 0 ? 0 : o.y) * 64u;
    const float* f2 = feat + (unsigned)(o.z < 0 ? 0 : o.z) * 64u;
    const float* f3 = feat + (unsigned)(o.w < 0 ? 0 : o.w) * 64u;
    // 0/1 masks to zero empty slots without divergence
    const float m0 = o.x >= 0 ? 1.0f : 0.0f;
    const float m1 = o.y >= 0 ? 1.0f : 0.0f;
    const float m2 = o.z >= 0 ? 1.0f : 0.0f;
    const float m3 = o.w >= 0 ? 1.0f : 0.0f;

    float* outp = out + (size_t)b * (C_ * HW_) + within;

    #pragma unroll
    for (int cc = 0; cc < C_; cc += 4) {
        float4 a = *(const float4*)(f0 + cc);
        float4 bq = *(const float4*)(f1 + cc);
        float4 cq = *(const float4*)(f2 + cc);
        float4 dq = *(const float4*)(f3 + cc);
        // 4x4 transpose: channel (cc+j) gets lane-quad {a[j],bq[j],cq[j],dq[j]}
        float4 w0 = make_float4(m0 * a.x, m1 * bq.x, m2 * cq.x, m3 * dq.x);
        float4 w1 = make_float4(m0 * a.y, m1 * bq.y, m2 * cq.y, m3 * dq.y);
        float4 w2 = make_float4(m0 * a.z, m1 * bq.z, m2 * cq.z, m3 * dq.z);
        float4 w3 = make_float4(m0 * a.w, m1 * bq.w, m2 * cq.w, m3 * dq.w);
        *(float4*)(outp + (size_t)(cc + 0) * HW_) = w0;
        *(float4*)(outp + (size_t)(cc + 1) * HW_) = w1;
        *(float4*)(outp + (size_t)(cc + 2) * HW_) = w2;
        *(float4*)(outp + (size_t)(cc + 3) * HW_) = w3;
    }
}

extern "C" void kernel_launch(void* const* d_in, const int* in_sizes, int n_in,
                              void* d_out, int out_size, void* d_ws, size_t ws_size,
                              hipStream_t stream) {
    const float* feat   = (const float*)d_in[0];   // [P,64] fp32
    const int*   coords = (const int*)d_in[1];     // [P,4] int32
    float*       out    = (float*)d_out;           // [8,64,496,432] fp32
    int*         owner  = (int*)d_ws;              // B*HW ints = 6.86 MB

    const int P = in_sizes[1] / 4;

    // pass 1: owner = -1 (d_ws is re-poisoned to 0xAA before every launch)
    const int n_owner  = B_ * HW_;                 // 1,714,176 (%4 == 0)
    const int n4_owner = n_owner / 4;
    pps_init_owner<<<(n4_owner + 255) / 256, 256, 0, stream>>>(owner, n4_owner);

    // pass 2: 200k atomicMax
    pps_scatter_owner<<<(P + 255) / 256, 256, 0, stream>>>(coords, owner, P);

    // pass 3: one thread per spatial quad, loops all 64 channels
    const int nquads = (B_ * HW_) / 4;             // 428,544
    pps_gather<<<(nquads + 255) / 256, 256, 0, stream>>>(feat, owner, out, nquads);
}

// Round 3
// 486.601 us; speedup vs baseline: 1.0010x; 1.0010x over previous
//
#include <hip/hip_runtime.h>

// PointPillarsScatter on MI355X.
// out[((b*C+c)*H+h)*W+w] = feat[owner(b, h*W+w), c], 0 where no owner.
// owner = argmax_p over pillars landing on the slot (last-wins overwrite
// semantics of sequential indexed assignment / jnp .at[].set()).
// Verified exact (absmax 0.0) in round 2.

#define B_  8
#define C_  64
#define H_  496
#define W_  432
#define HW_ (H_ * W_)          // 214272 (divisible by 4)

typedef int   v4i __attribute__((ext_vector_type(4)));
typedef float v4f __attribute__((ext_vector_type(4)));

// ---- pass 1: owner map = -1 --------------------------------------------
__global__ void pps_init_owner(int* __restrict__ owner, int n4) {
    int t = blockIdx.x * blockDim.x + threadIdx.x;
    if (t < n4) {
        v4i m1 = {-1, -1, -1, -1};
        __builtin_nontemporal_store(m1, (v4i*)owner + t);
    }
}

// ---- pass 2: last-wins slot ownership via atomicMax --------------------
__global__ void pps_scatter_owner(const int* __restrict__ coords,
                                  int* __restrict__ owner, int P) {
    int p = blockIdx.x * blockDim.x + threadIdx.x;
    if (p >= P) return;
    v4i c = ((const v4i*)coords)[p];         // (b, x, y, z)
    int idx = c.y * W_ + c.z;
    idx = min(max(idx, 0), HW_ - 1);         // clip, as in reference
    atomicMax(&owner[c.x * HW_ + idx], p);   // device-scope by default
}

// ---- pass 3: channel-loop gather, fuses zero-fill ----------------------
// One thread = 4 consecutive spatial positions x all 64 channels.
// Owner map read exactly once; each pillar feature row read by exactly one
// thread (rows stream through L1 across the cc loop).
// unroll 4 (not full): caps in-flight loads at 16 float4 -> no spill.
__global__ __launch_bounds__(256) void pps_gather(
        const float* __restrict__ feat,      // [P, 64]
        const int*   __restrict__ owner,     // [B*HW]
        float*       __restrict__ out,       // [B, C, H, W]
        int nquads) {                        // B*HW/4
    int t = blockIdx.x * blockDim.x + threadIdx.x;
    if (t >= nquads) return;
    unsigned pos    = (unsigned)t * 4u;      // b*HW + within, %4 == 0
    unsigned b      = pos / HW_;             // magic-mul
    unsigned within = pos - b * HW_;         // quads never cross b (HW_%4==0)

    v4i o = __builtin_nontemporal_load((const v4i*)&owner[pos]);
    const float* f0 = feat + (unsigned)max(o.x, 0) * 64u;
    const float* f1 = feat + (unsigned)max(o.y, 0) * 64u;
    const float* f2 = feat + (unsigned)max(o.z, 0) * 64u;
    const float* f3 = feat + (unsigned)max(o.w, 0) * 64u;
    // 0/1 masks zero the empty slots without divergence
    const float m0 = o.x >= 0 ? 1.0f : 0.0f;
    const float m1 = o.y >= 0 ? 1.0f : 0.0f;
    const float m2 = o.z >= 0 ? 1.0f : 0.0f;
    const float m3 = o.w >= 0 ? 1.0f : 0.0f;

    float* outp = out + (size_t)b * (C_ * HW_) + within;

    #pragma unroll 4
    for (int cc = 0; cc < C_; cc += 4) {
        v4f a  = *(const v4f*)(f0 + cc);
        v4f bq = *(const v4f*)(f1 + cc);
        v4f cq = *(const v4f*)(f2 + cc);
        v4f dq = *(const v4f*)(f3 + cc);
        // 4x4 transpose: channel (cc+j) gets lane-quad {a[j],bq[j],cq[j],dq[j]}
        v4f w0 = {m0 * a.x, m1 * bq.x, m2 * cq.x, m3 * dq.x};
        v4f w1 = {m0 * a.y, m1 * bq.y, m2 * cq.y, m3 * dq.y};
        v4f w2 = {m0 * a.z, m1 * bq.z, m2 * cq.z, m3 * dq.z};
        v4f w3 = {m0 * a.w, m1 * bq.w, m2 * cq.w, m3 * dq.w};
        __builtin_nontemporal_store(w0, (v4f*)(outp + (size_t)(cc + 0) * HW_));
        __builtin_nontemporal_store(w1, (v4f*)(outp + (size_t)(cc + 1) * HW_));
        __builtin_nontemporal_store(w2, (v4f*)(outp + (size_t)(cc + 2) * HW_));
        __builtin_nontemporal_store(w3, (v4f*)(outp + (size_t)(cc + 3) * HW_));
    }
}

extern "C" void kernel_launch(void* const* d_in, const int* in_sizes, int n_in,
                              void* d_out, int out_size, void* d_ws, size_t ws_size,
                              hipStream_t stream) {
    const float* feat   = (const float*)d_in[0];   // [P,64] fp32
    const int*   coords = (const int*)d_in[1];     // [P,4] int32
    float*       out    = (float*)d_out;           // [8,64,496,432] fp32
    int*         owner  = (int*)d_ws;              // B*HW ints = 6.86 MB

    const int P = in_sizes[1] / 4;

    // pass 1: owner = -1
    const int n_owner  = B_ * HW_;                 // 1,714,176 (%4 == 0)
    const int n4_owner = n_owner / 4;
    pps_init_owner<<<(n4_owner + 255) / 256, 256, 0, stream>>>(owner, n4_owner);

    // pass 2: 200k atomicMax
    pps_scatter_owner<<<(P + 255) / 256, 256, 0, stream>>>(coords, owner, P);

    // pass 3: one thread per spatial quad, loops all 64 channels
    const int nquads = (B_ * HW_) / 4;             // 428,544
    pps_gather<<<(nquads + 255) / 256, 256, 0, stream>>>(feat, owner, out, nquads);
}